// Round 3
// baseline (13218.506 us; speedup 1.0000x reference)
//
#include <hip/hip_runtime.h>
#include <hip/hip_bf16.h>
#include <stdint.h>

typedef __attribute__((ext_vector_type(8))) short short8;
typedef __attribute__((ext_vector_type(4))) float f32x4;
typedef unsigned short u16;
typedef unsigned int   u32;
typedef unsigned long long u64;

#define DEV static __device__ __forceinline__

DEV float bf2f(u16 u){ return __uint_as_float((u32)u << 16); }
DEV u16 f2bf(float f){ u32 i = __float_as_uint(f); return (u16)((i + 0x7FFFu + ((i>>16)&1u)) >> 16); }
DEV float sigmoid_(float x){ return 1.f/(1.f + __expf(-x)); }
DEV float tanh_(float x){ float a=fabsf(x); float e=__expf(-2.f*a); float r=(1.f-e)/(1.f+e); return x<0.f? -r:r; }
DEV float silu_(float x){ return x/(1.f + __expf(-x)); }

DEV void gload_lds16(const u16* g, u16* l){
  __builtin_amdgcn_global_load_lds((const __attribute__((address_space(1))) void*)g,
                                   (__attribute__((address_space(3))) void*)l, 16, 0, 0);
}

// ---------------- problem constants ----------------
// B=16 H=48 W=48 C=384, L=2304, d_inner=768, hid=384, 3h=1152
#define LSEQ 2304
#define NCOL 5376
#define NCHUNK 20
#define WARM 48

// ---------------- GEMM: C[m][n] = sum_k A[m][k]*B[n][k]  (A,B bf16 [*,K] k-contig) ----------------
// EPI: 0 = plain bf16 store, 1 = +bias[n] bf16 store, 2 = +resid[m*N+n] fp32 -> FP32 store
template<int EPI>
__global__ __launch_bounds__(512, 2)
void k_gemm(const u16* __restrict__ A, const u16* __restrict__ Bm, u16* __restrict__ Cout,
            float* __restrict__ Fout,
            const float* __restrict__ bias, const float* __restrict__ resid, int K_)
{
  __shared__ u16 ldsA[128*64];
  __shared__ u16 ldsB[128*64];
  const int N   = gridDim.y * 128;
  const int tid = threadIdx.x, l = tid & 63, wid = tid >> 6;
  const int wm = wid >> 2, wn = wid & 3;          // 2 x 4 wave grid, wave tile 64x32
  const int bm = blockIdx.x, bn = blockIdx.y;
  const int jl = l & 15, kq = l >> 4;

  f32x4 acc[4][2];
  #pragma unroll
  for (int a=0;a<4;++a)
    #pragma unroll
    for (int b=0;b<2;++b) acc[a][b] = (f32x4){0.f,0.f,0.f,0.f};

  const u16* Abase = A  + (size_t)bm*128*K_;
  const u16* Bbase = Bm + (size_t)bn*128*K_;
  const int nK = K_ >> 6;
  for (int ks=0; ks<nK; ++ks) {
    __syncthreads();                               // previous frag reads done
    #pragma unroll
    for (int p=0;p<2;++p) {
      int row = p*64 + wid*8 + (l>>3);
      int ch  = l & 7;
      // source pre-swizzled so linear LDS holds XOR-swizzled layout (bank-conflict-free reads)
      gload_lds16(Abase + (size_t)row*K_ + ks*64 + ((ch ^ (row&7))<<3), ldsA + p*4096 + wid*512);
      gload_lds16(Bbase + (size_t)row*K_ + ks*64 + ((ch ^ (row&7))<<3), ldsB + p*4096 + wid*512);
    }
    __syncthreads();                               // drains vmcnt -> staging complete
    #pragma unroll
    for (int kt=0; kt<2; ++kt) {
      short8 av[4], bv[2];
      #pragma unroll
      for (int mt=0; mt<4; ++mt) {
        int r = wm*64 + mt*16 + jl;
        int c = kt*4 + kq;
        av[mt] = *(const short8*)(ldsA + r*64 + ((c ^ (r&7))<<3));
      }
      #pragma unroll
      for (int nt=0; nt<2; ++nt) {
        int r = wn*32 + nt*16 + jl;
        int c = kt*4 + kq;
        bv[nt] = *(const short8*)(ldsB + r*64 + ((c ^ (r&7))<<3));
      }
      #pragma unroll
      for (int mt=0; mt<4; ++mt)
        #pragma unroll
        for (int nt=0; nt<2; ++nt)
          acc[mt][nt] = __builtin_amdgcn_mfma_f32_16x16x32_bf16(av[mt], bv[nt], acc[mt][nt], 0,0,0);
    }
  }
  #pragma unroll
  for (int mt=0; mt<4; ++mt)
    #pragma unroll
    for (int nt=0; nt<2; ++nt)
      #pragma unroll
      for (int i=0;i<4;++i) {
        int m = bm*128 + wm*64 + mt*16 + kq*4 + i;   // D row = (lane>>4)*4+reg
        int n = bn*128 + wn*32 + nt*16 + jl;         // D col = lane&15
        float v = acc[mt][nt][i];
        if (EPI==1) v += bias[n];
        if (EPI==2) {
          v += resid[(size_t)m*N + n];
          Fout[(size_t)m*N + n] = v;                 // fp32 output (reference returns f32)
        } else {
          Cout[(size_t)m*N + n] = f2bf(v);
        }
      }
}

// ---------------- LayerNorm: one wave per row of 384 ----------------
__global__ __launch_bounds__(256)
void k_ln(const float* __restrict__ x, const float* __restrict__ gg, const float* __restrict__ bb,
          u16* __restrict__ xn)
{
  const int row = blockIdx.x*4 + (threadIdx.x>>6);
  const int l = threadIdx.x & 63;
  const float* xr = x + (size_t)row*384;
  float v[6]; float s = 0.f, q = 0.f;
  #pragma unroll
  for (int k=0;k<6;++k){ v[k] = xr[l + 64*k]; s += v[k]; q += v[k]*v[k]; }
  #pragma unroll
  for (int off=32; off; off>>=1){ s += __shfl_xor(s, off); q += __shfl_xor(q, off); }
  const float mean = s * (1.f/384.f);
  const float var  = q * (1.f/384.f) - mean*mean;
  const float rs   = rsqrtf(var + 1e-5f);
  u16* o = xn + (size_t)row*384;
  #pragma unroll
  for (int k=0;k<6;++k){ int c = l + 64*k; o[c] = f2bf((v[k]-mean)*rs*gg[c] + bb[c]); }
}

// ---------------- small converts ----------------
__global__ void k_cvt_wih(const float* a0,const float* a1,const float* a2,const float* a3, u16* out){
  const int per = 1152*768;
  for (int i = blockIdx.x*blockDim.x + threadIdx.x; i < 4*per; i += gridDim.x*blockDim.x) {
    int dd = i / per; int rem = i - dd*per;
    const float* s = dd==0?a0 : dd==1?a1 : dd==2?a2 : a3;
    out[i] = f2bf(s[rem]);
  }
}
__global__ void k_tr_winx(const float* w_in, u16* out){        // out[c*768+k] = w_in[k*384+c], k<768
  for (int i = blockIdx.x*blockDim.x + threadIdx.x; i < 384*768; i += gridDim.x*blockDim.x) {
    int c = i / 768, k = i - c*768;
    out[i] = f2bf(w_in[(size_t)k*384 + c]);
  }
}
__global__ void k_cvt_winz(const float* w_in, u16* dst){        // rows 768..1535 of w_in, contig
  for (int i = blockIdx.x*blockDim.x + threadIdx.x; i < 768*384; i += gridDim.x*blockDim.x)
    dst[i] = f2bf(w_in[768*384 + i]);
}
__global__ void k_cvt_wout(const float* w_out, u16* dst){       // [384][768] direct
  for (int i = blockIdx.x*blockDim.x + threadIdx.x; i < 384*768; i += gridDim.x*blockDim.x)
    dst[i] = f2bf(w_out[i]);
}
__global__ void k_bias(const float* b0,const float* b1,const float* b2,const float* b3, float* bias){
  for (int i = blockIdx.x*blockDim.x + threadIdx.x; i < NCOL; i += gridDim.x*blockDim.x) {
    float v = 0.f;
    if (i < 4608) { int dd = i/1152, r = i - dd*1152;
      v = (dd==0?b0: dd==1?b1: dd==2?b2: b3)[r]; }
    bias[i] = v;
  }
}

// ---------------- the chunked GRU scan ----------------
// 80 units (4 dirs x 20 chunks), 3 WGs/unit (j-slices of 128), 512 thr/WG, whh in registers.
// MFMA A rows = Bp batches x (16/Bp) sub-chunks; per-row independent recurrence.
// launch_bounds(512,1): VGPR cap 256 (wf alone = 144; (512,2) would spill). 240 blocks @ 1/CU co-resident.
__global__ __launch_bounds__(512, 1)
void k_scan(const float* __restrict__ whh0, const float* __restrict__ whh1,
            const float* __restrict__ whh2, const float* __restrict__ whh3,
            const float* __restrict__ bhh0, const float* __restrict__ bhh1,
            const float* __restrict__ bhh2, const float* __restrict__ bhh3,
            const u16* __restrict__ gxz, u16* __restrict__ hbuf,
            u16* xchg, int* flags, int Bp, int lbp, int CHL)
{
  const int blk = blockIdx.x;
  const int g = blk/24, r8 = blk%24, x8 = r8&7, p = r8>>3;  // XCD-grouping heuristic only
  const int unit = g*8 + x8;
  const int d = unit & 3, chunk = unit >> 2;
  const bool fw = (d==0) || (d==3);                         // dirs 1,2 are reverse scans

  const float* whh = d==0?whh0 : d==1?whh1 : d==2?whh2 : whh3;
  const float* bhh = d==0?bhh0 : d==1?bhh1 : d==2?bhh2 : bhh3;

  const int tid = threadIdx.x, l = tid & 63, w = tid >> 6;
  const int jl = l & 15, kq = l >> 4;
  const int j = p*128 + w*16 + jl;                          // this lane's hidden index

  __shared__ u16 hlds[16*392];                              // h bf16 [16 rows][384+pad]
  for (int i = tid; i < 16*392; i += 512) hlds[i] = 0;

  // register-resident whh B-fragments: wave owns gate-triple rows {j, 384+j, 768+j}
  short8 wf[3][12];
  #pragma unroll
  for (int g3=0; g3<3; ++g3) {
    const float* src = whh + (size_t)(g3*384 + j)*384 + kq*8;
    #pragma unroll
    for (int kt=0; kt<12; ++kt) {
      short8 t;
      #pragma unroll
      for (int e=0;e<8;++e) t[e] = (short)f2bf(src[kt*32 + e]);
      wf[g3][kt] = t;
    }
  }
  float bh[3];
  #pragma unroll
  for (int g3=0; g3<3; ++g3) bh[g3] = bhh[g3*384 + j];
  int colb[3];
  #pragma unroll
  for (int g3=0; g3<3; ++g3) colb[g3] = d*1152 + g3*384 + j;

  // per-A-row (r = kq*4+i) scan geometry
  int cs_[4], ce_[4], tb_[4], br_[4];
  #pragma unroll
  for (int i=0;i<4;++i) {
    int r = kq*4 + i;
    int b = r & (Bp-1);
    int sub = r >> lbp;
    int scid = chunk*(16>>lbp) + sub;
    int cs = scid*CHL;
    int ce = min(LSEQ, cs + CHL);
    cs_[i]=cs; ce_[i]=ce; br_[i]=b;
    tb_[i] = fw ? (cs - WARM) : (ce - 1 + WARM);
  }
  const int nsteps = WARM + CHL;

  float hp[4] = {0.f,0.f,0.f,0.f};
  const int slice = unit*3 + p;
  int* uflag = flags + unit*3;

  u16 gxu[12], gxn[12];
  #pragma unroll
  for (int i=0;i<4;++i) {
    int tl = min(LSEQ-1, max(0, tb_[i]));
    const size_t ro = ((size_t)br_[i]*LSEQ + tl)*NCOL;
    #pragma unroll
    for (int g3=0; g3<3; ++g3) gxu[i*3+g3] = gxz[ro + colb[g3]];
  }

  __syncthreads();

  for (int s=0; s<nsteps; ++s) {
    // gh = h @ whh^T + bhh  via MFMA (A = h bf16 from LDS, B = register weights)
    f32x4 acc[3];
    #pragma unroll
    for (int g3=0; g3<3; ++g3) { f32x4 a; a[0]=a[1]=a[2]=a[3]=bh[g3]; acc[g3]=a; }
    #pragma unroll
    for (int kt=0; kt<12; ++kt) {
      short8 av = *(const short8*)(hlds + jl*392 + kt*32 + kq*8);
      #pragma unroll
      for (int g3=0; g3<3; ++g3)
        acc[g3] = __builtin_amdgcn_mfma_f32_16x16x32_bf16(av, wf[g3][kt], acc[g3], 0,0,0);
    }
    // gates: lane owns (row kq*4+i, hidden j)
    u16 hb[4];
    #pragma unroll
    for (int i=0;i<4;++i) {
      const int t = fw ? (tb_[i] + s) : (tb_[i] - s);
      float rr = sigmoid_(bf2f(gxu[i*3+0]) + acc[0][i]);
      float zz = sigmoid_(bf2f(gxu[i*3+1]) + acc[1][i]);
      float nn = tanh_(bf2f(gxu[i*3+2]) + rr*acc[2][i]);
      float hv = nn + zz*(hp[i]-nn);
      const bool invalid = fw ? (t < 0) : (t > LSEQ-1);
      hv = invalid ? 0.f : hv;
      hp[i] = hv;
      hb[i] = f2bf(hv);
      if (t >= cs_[i] && t < ce_[i])
        hbuf[(((size_t)d*Bp + br_[i])*LSEQ + t)*384 + j] = hb[i];
    }
    if (s+1 < nsteps) {
      const int par = s & 1;                               // parity double-buffer (race fix)
      // prefetch next step's gx while we do the exchange
      #pragma unroll
      for (int i=0;i<4;++i) {
        const int t = fw ? (tb_[i] + s + 1) : (tb_[i] - s - 1);
        const int tl = min(LSEQ-1, max(0, t));
        const size_t ro = ((size_t)br_[i]*LSEQ + tl)*NCOL;
        #pragma unroll
        for (int g3=0; g3<3; ++g3) gxn[i*3+g3] = gxz[ro + colb[g3]];
      }
      __syncthreads();                                     // all A-frag reads of h_{s-1} done
      #pragma unroll
      for (int i=0;i<4;++i) hlds[(kq*4+i)*392 + j] = hb[i];
      u64 pk = (u64)hb[0] | ((u64)hb[1]<<16) | ((u64)hb[2]<<32) | ((u64)hb[3]<<48);
      __hip_atomic_store((u64*)(xchg + (size_t)(slice*2 + par)*2048) + ((w*16+jl)*4 + kq), pk,
                         __ATOMIC_RELAXED, __HIP_MEMORY_SCOPE_AGENT);
      __syncthreads();                                     // drains ds + vm stores
      if (tid == 0)
        __hip_atomic_store(uflag + p, s+1, __ATOMIC_RELEASE, __HIP_MEMORY_SCOPE_AGENT);
      #pragma unroll
      for (int qi=1; qi<3; ++qi) {
        int q = p + qi; if (q >= 3) q -= 3;
        int guard = 0;
        while (__hip_atomic_load(uflag + q, __ATOMIC_ACQUIRE, __HIP_MEMORY_SCOPE_AGENT) < s+1) {
          __builtin_amdgcn_s_sleep(2);
          if (++guard > (1<<22)) break;                    // bounded: garbage beats a hang
        }
      }
      #pragma unroll
      for (int qi=1; qi<3; ++qi) {
        int q = p + qi; if (q >= 3) q -= 3;
        const u64 v = __hip_atomic_load((const u64*)(xchg + (size_t)((unit*3+q)*2 + par)*2048) + tid,
                                        __ATOMIC_RELAXED, __HIP_MEMORY_SCOPE_AGENT);
        const int jloc = tid >> 2, b0 = (tid & 3)*4;
        const int jg = q*128 + jloc;
        hlds[(b0+0)*392 + jg] = (u16)(v);
        hlds[(b0+1)*392 + jg] = (u16)(v>>16);
        hlds[(b0+2)*392 + jg] = (u16)(v>>32);
        hlds[(b0+3)*392 + jg] = (u16)(v>>48);
      }
      __syncthreads();                                     // h_s complete in LDS
      #pragma unroll
      for (int i=0;i<12;++i) gxu[i] = gxn[i];
    }
  }
}

// ---------------- combine: y = silu(h_a + h_b) * silu(z) ----------------
__global__ __launch_bounds__(256)
void k_combine(const u16* __restrict__ hbuf, const u16* __restrict__ gxz, u16* __restrict__ y, int Bp)
{
  const int e = blockIdx.x*256 + threadIdx.x;              // 0 .. Bp*2304*96-1 exact
  const int rowi = e / 96;
  const int c8 = e - rowi*96;
  const int jp0 = c8*8;
  const int bb = rowi / LSEQ, ll = rowi - bb*LSEQ;
  const int da = jp0 < 384 ? 0 : 1;
  const int j0 = jp0 < 384 ? jp0 : jp0 - 384;
  const short8 va = *(const short8*)(hbuf + (((size_t)da*Bp + bb)*LSEQ + ll)*384 + j0);
  const short8 vb = *(const short8*)(hbuf + (((size_t)(da+2)*Bp + bb)*LSEQ + ll)*384 + j0);
  const short8 vz = *(const short8*)(gxz + (size_t)rowi*NCOL + 4608 + jp0);
  short8 vo;
  #pragma unroll
  for (int k=0;k<8;++k) {
    float a = bf2f((u16)va[k]) + bf2f((u16)vb[k]);
    vo[k] = (short)f2bf(silu_(a) * silu_(bf2f((u16)vz[k])));
  }
  *(short8*)(y + (size_t)rowi*768 + jp0) = vo;
}

// ---------------- launch ----------------
extern "C" void kernel_launch(void* const* d_in, const int* in_sizes, int n_in,
                              void* d_out, int out_size, void* d_ws, size_t ws_size,
                              hipStream_t stream)
{
  const float* x     = (const float*)d_in[0];
  const float* ln_g  = (const float*)d_in[1];
  const float* ln_b  = (const float*)d_in[2];
  const float* w_in  = (const float*)d_in[3];
  const float* w_out = (const float*)d_in[4];
  const float* wih[4] = {(const float*)d_in[5], (const float*)d_in[9],  (const float*)d_in[13], (const float*)d_in[17]};
  const float* whh[4] = {(const float*)d_in[6], (const float*)d_in[10], (const float*)d_in[14], (const float*)d_in[18]};
  const float* bih[4] = {(const float*)d_in[7], (const float*)d_in[11], (const float*)d_in[15], (const float*)d_in[19]};
  const float* bhh[4] = {(const float*)d_in[8], (const float*)d_in[12], (const float*)d_in[16], (const float*)d_in[20]};

  auto al = [](size_t v)->size_t { return (v + 255) & ~(size_t)255; };
  const size_t fixed = al(7077888) + al(589824) + al(589824) + al(4128768) + al(21504)
                     + al((size_t)240*4096*2) + al(1024);
  auto req = [&](int bp)->size_t {
    return fixed + al((size_t)bp*LSEQ*NCOL*2)           // gxz
                 + al((size_t)bp*4*LSEQ*384*2)          // hbuf
                 + al((size_t)bp*LSEQ*768*2);           // y (xn aliases y)
  };
  int Bp = 1;
  for (int bp = 16; bp >= 1; bp >>= 1) { if (req(bp) <= ws_size) { Bp = bp; break; } }
  if (req(1) > ws_size) return;                         // cannot run at all (diagnostic)
  int lbp = 0; while ((1<<lbp) < Bp) ++lbp;
  const int SC  = NCHUNK*(16/Bp);                       // sub-chunks per direction
  const int CHL = (LSEQ + SC - 1)/SC;

  char* ws = (char*)d_ws;
  size_t o = 0;
  auto take = [&](size_t bytes)->char* { char* r = ws + o; o += al(bytes); return r; };
  u16*  wihcat = (u16*)take(7077888);
  u16*  winxT  = (u16*)take(589824);
  u16*  woutB  = (u16*)take(589824);
  u16*  Wcat   = (u16*)take(4128768);
  float* biasf = (float*)take(21504);
  u16*  xchgp  = (u16*)take((size_t)240*4096*2);        // 240 slices x 2 parity x 4KB
  int*  flagsp = (int*)take(1024);
  u16*  gxzp   = (u16*)take((size_t)Bp*LSEQ*NCOL*2);
  u16*  hbufp  = (u16*)take((size_t)Bp*4*LSEQ*384*2);
  u16*  yp     = (u16*)take((size_t)Bp*LSEQ*768*2);
  u16*  xnp    = yp;                                    // xn dead before y is written

  // one-time weight prep
  k_cvt_wih <<<4096, 256, 0, stream>>>(wih[0],wih[1],wih[2],wih[3], wihcat);
  k_tr_winx <<<1152, 256, 0, stream>>>(w_in, winxT);
  k_cvt_winz<<<1152, 256, 0, stream>>>(w_in, Wcat + (size_t)4608*384);
  k_cvt_wout<<<1152, 256, 0, stream>>>(w_out, woutB);
  k_bias    <<<21,   256, 0, stream>>>(bih[0],bih[1],bih[2],bih[3], biasf);
  // W_comb = wih_all @ w_in_x : [4608,384]
  k_gemm<0><<<dim3(36,3), 512, 0, stream>>>(wihcat, winxT, Wcat, nullptr, nullptr, nullptr, 768);

  const int npass = 16 / Bp;
  for (int pass = 0; pass < npass; ++pass) {
    const size_t b0row = (size_t)pass * Bp * LSEQ;      // global row offset
    k_ln <<<Bp*576, 256, 0, stream>>>(x + b0row*384, ln_g, ln_b, xnp);
    // gx||z = xn @ Wcat^T + bias : [Bp*2304, 5376]
    k_gemm<1><<<dim3(Bp*18,42), 512, 0, stream>>>(xnp, Wcat, gxzp, nullptr, biasf, nullptr, 384);
    hipMemsetAsync(flagsp, 0, 1024, stream);
    k_scan <<<240, 512, 0, stream>>>(whh[0],whh[1],whh[2],whh[3],
                                     bhh[0],bhh[1],bhh[2],bhh[3],
                                     gxzp, hbufp, xchgp, flagsp, Bp, lbp, CHL);
    k_combine <<<Bp*864, 256, 0, stream>>>(hbufp, gxzp, yp, Bp);
    // out = x + y @ w_out^T  (FP32 store to d_out)
    k_gemm<2><<<dim3(Bp*18,3), 512, 0, stream>>>(yp, woutB, nullptr, (float*)d_out + b0row*384,
                                                 nullptr, x + b0row*384, 768);
  }
}

// Round 4
// 6831.889 us; speedup vs baseline: 1.9348x; 1.9348x over previous
//
#include <hip/hip_runtime.h>
#include <hip/hip_bf16.h>
#include <stdint.h>

typedef __attribute__((ext_vector_type(8))) short short8;
typedef __attribute__((ext_vector_type(4))) float f32x4;
typedef unsigned short u16;
typedef unsigned int   u32;
typedef unsigned long long u64;

#define DEV static __device__ __forceinline__

DEV float bf2f(u16 u){ return __uint_as_float((u32)u << 16); }
DEV u16 f2bf(float f){ u32 i = __float_as_uint(f); return (u16)((i + 0x7FFFu + ((i>>16)&1u)) >> 16); }
DEV float sigmoid_(float x){ return 1.f/(1.f + __expf(-x)); }
DEV float tanh_(float x){ float a=fabsf(x); float e=__expf(-2.f*a); float r=(1.f-e)/(1.f+e); return x<0.f? -r:r; }
DEV float silu_(float x){ return x/(1.f + __expf(-x)); }

DEV void gload_lds16(const u16* g, u16* l){
  __builtin_amdgcn_global_load_lds((const __attribute__((address_space(1))) void*)g,
                                   (__attribute__((address_space(3))) void*)l, 16, 0, 0);
}

// ---------------- problem constants ----------------
// B=16 H=48 W=48 C=384, L=2304, d_inner=768, hid=384, 3h=1152
#define LSEQ 2304
#define NCOL 5376
#define NCHUNK 60          // units per direction (single-WG units)
#define WARM 32

// ---------------- GEMM: C[m][n] = sum_k A[m][k]*B[n][k]  (A,B bf16 [*,K] k-contig) ----------------
// EPI: 0 = plain bf16 store, 1 = +bias[n] bf16 store, 2 = +resid[m*N+n] fp32 -> FP32 store
template<int EPI>
__global__ __launch_bounds__(512, 2)
void k_gemm(const u16* __restrict__ A, const u16* __restrict__ Bm, u16* __restrict__ Cout,
            float* __restrict__ Fout,
            const float* __restrict__ bias, const float* __restrict__ resid, int K_)
{
  __shared__ u16 ldsA[128*64];
  __shared__ u16 ldsB[128*64];
  const int N   = gridDim.y * 128;
  const int tid = threadIdx.x, l = tid & 63, wid = tid >> 6;
  const int wm = wid >> 2, wn = wid & 3;          // 2 x 4 wave grid, wave tile 64x32
  const int bm = blockIdx.x, bn = blockIdx.y;
  const int jl = l & 15, kq = l >> 4;

  f32x4 acc[4][2];
  #pragma unroll
  for (int a=0;a<4;++a)
    #pragma unroll
    for (int b=0;b<2;++b) acc[a][b] = (f32x4){0.f,0.f,0.f,0.f};

  const u16* Abase = A  + (size_t)bm*128*K_;
  const u16* Bbase = Bm + (size_t)bn*128*K_;
  const int nK = K_ >> 6;
  for (int ks=0; ks<nK; ++ks) {
    __syncthreads();
    #pragma unroll
    for (int p=0;p<2;++p) {
      int row = p*64 + wid*8 + (l>>3);
      int ch  = l & 7;
      gload_lds16(Abase + (size_t)row*K_ + ks*64 + ((ch ^ (row&7))<<3), ldsA + p*4096 + wid*512);
      gload_lds16(Bbase + (size_t)row*K_ + ks*64 + ((ch ^ (row&7))<<3), ldsB + p*4096 + wid*512);
    }
    __syncthreads();
    #pragma unroll
    for (int kt=0; kt<2; ++kt) {
      short8 av[4], bv[2];
      #pragma unroll
      for (int mt=0; mt<4; ++mt) {
        int r = wm*64 + mt*16 + jl;
        int c = kt*4 + kq;
        av[mt] = *(const short8*)(ldsA + r*64 + ((c ^ (r&7))<<3));
      }
      #pragma unroll
      for (int nt=0; nt<2; ++nt) {
        int r = wn*32 + nt*16 + jl;
        int c = kt*4 + kq;
        bv[nt] = *(const short8*)(ldsB + r*64 + ((c ^ (r&7))<<3));
      }
      #pragma unroll
      for (int mt=0; mt<4; ++mt)
        #pragma unroll
        for (int nt=0; nt<2; ++nt)
          acc[mt][nt] = __builtin_amdgcn_mfma_f32_16x16x32_bf16(av[mt], bv[nt], acc[mt][nt], 0,0,0);
    }
  }
  #pragma unroll
  for (int mt=0; mt<4; ++mt)
    #pragma unroll
    for (int nt=0; nt<2; ++nt)
      #pragma unroll
      for (int i=0;i<4;++i) {
        int m = bm*128 + wm*64 + mt*16 + kq*4 + i;   // D row = (lane>>4)*4+reg
        int n = bn*128 + wn*32 + nt*16 + jl;         // D col = lane&15
        float v = acc[mt][nt][i];
        if (EPI==1) v += bias[n];
        if (EPI==2) {
          v += resid[(size_t)m*N + n];
          Fout[(size_t)m*N + n] = v;                 // fp32 output
        } else {
          Cout[(size_t)m*N + n] = f2bf(v);
        }
      }
}

// ---------------- LayerNorm: one wave per row of 384 ----------------
__global__ __launch_bounds__(256)
void k_ln(const float* __restrict__ x, const float* __restrict__ gg, const float* __restrict__ bb,
          u16* __restrict__ xn)
{
  const int row = blockIdx.x*4 + (threadIdx.x>>6);
  const int l = threadIdx.x & 63;
  const float* xr = x + (size_t)row*384;
  float v[6]; float s = 0.f, q = 0.f;
  #pragma unroll
  for (int k=0;k<6;++k){ v[k] = xr[l + 64*k]; s += v[k]; q += v[k]*v[k]; }
  #pragma unroll
  for (int off=32; off; off>>=1){ s += __shfl_xor(s, off); q += __shfl_xor(q, off); }
  const float mean = s * (1.f/384.f);
  const float var  = q * (1.f/384.f) - mean*mean;
  const float rs   = rsqrtf(var + 1e-5f);
  u16* o = xn + (size_t)row*384;
  #pragma unroll
  for (int k=0;k<6;++k){ int c = l + 64*k; o[c] = f2bf((v[k]-mean)*rs*gg[c] + bb[c]); }
}

// ---------------- small converts ----------------
__global__ void k_cvt_wih(const float* a0,const float* a1,const float* a2,const float* a3, u16* out){
  const int per = 1152*768;
  for (int i = blockIdx.x*blockDim.x + threadIdx.x; i < 4*per; i += gridDim.x*blockDim.x) {
    int dd = i / per; int rem = i - dd*per;
    const float* s = dd==0?a0 : dd==1?a1 : dd==2?a2 : a3;
    out[i] = f2bf(s[rem]);
  }
}
__global__ void k_tr_winx(const float* w_in, u16* out){        // out[c*768+k] = w_in[k*384+c], k<768
  for (int i = blockIdx.x*blockDim.x + threadIdx.x; i < 384*768; i += gridDim.x*blockDim.x) {
    int c = i / 768, k = i - c*768;
    out[i] = f2bf(w_in[(size_t)k*384 + c]);
  }
}
__global__ void k_cvt_winz(const float* w_in, u16* dst){
  for (int i = blockIdx.x*blockDim.x + threadIdx.x; i < 768*384; i += gridDim.x*blockDim.x)
    dst[i] = f2bf(w_in[768*384 + i]);
}
__global__ void k_cvt_wout(const float* w_out, u16* dst){
  for (int i = blockIdx.x*blockDim.x + threadIdx.x; i < 384*768; i += gridDim.x*blockDim.x)
    dst[i] = f2bf(w_out[i]);
}
__global__ void k_bias(const float* b0,const float* b1,const float* b2,const float* b3, float* bias){
  for (int i = blockIdx.x*blockDim.x + threadIdx.x; i < NCOL; i += gridDim.x*blockDim.x) {
    float v = 0.f;
    if (i < 4608) { int dd = i/1152, r = i - dd*1152;
      v = (dd==0?b0: dd==1?b1: dd==2?b2: b3)[r]; }
    bias[i] = v;
  }
}

// ---------------- pack whh into MFMA B-fragment order ----------------
// wp[((d*72 + nt)*12 + kt)*512 + l*8 + e] = bf16(whh_d[nt*16 + (l&15)][kt*32 + (l>>4)*8 + e])
// -> a wave's frag load is lanes 0..63 x contiguous 16B = one coalesced 1KB dwordx4 burst.
__global__ void k_pack(const float* w0,const float* w1,const float* w2,const float* w3, u16* wp){
  int idx = blockIdx.x*256 + threadIdx.x;          // 4*72*12*64 = 221184 lane-slots
  if (idx >= 4*72*12*64) return;
  int l = idx & 63; int t = idx >> 6;
  int kt = t % 12; t /= 12;
  int nt = t % 72; int d = t / 72;
  const float* w = d==0?w0 : d==1?w1 : d==2?w2 : w3;
  int row = nt*16 + (l&15);
  int k0  = kt*32 + (l>>4)*8;
  u16* o = wp + (size_t)idx*8;
  #pragma unroll
  for (int e=0;e<8;++e) o[e] = f2bf(w[(size_t)row*384 + k0 + e]);
}

// ---------------- single-WG chunked GRU scan (no cross-WG sync) ----------------
// 240 WGs = 4 dirs x 60 units. One WG owns all 384 hidden dims for 16 rows
// (Bp batches x 16/Bp sub-chunks). whh streamed from L2 every step (pre-packed frags);
// gx/hbuf use nontemporal accesses so they cannot evict the L2-resident weights.
__global__ __launch_bounds__(512, 1)
void k_scan2(const u16* __restrict__ wpack,
             const float* __restrict__ bhh0, const float* __restrict__ bhh1,
             const float* __restrict__ bhh2, const float* __restrict__ bhh3,
             const u16* __restrict__ gxz, u16* __restrict__ hbuf,
             int Bp, int lbp, int CHL)
{
  const int blk = blockIdx.x;
  const int d  = blk & 3;                 // dir; blk%8 -> XCD heuristic gives dir-per-XCD L2 affinity
  const int uk = blk >> 2;                // unit index within dir, [0,60)
  const bool fw = (d==0) || (d==3);

  const float* bhh = d==0?bhh0 : d==1?bhh1 : d==2?bhh2 : bhh3;

  const int tid = threadIdx.x, l = tid & 63, w = tid >> 6;   // 8 waves
  const int jl = l & 15, kq = l >> 4;

  __shared__ u16 hlds[16*392];            // h bf16 [16 rows][384+pad]
  for (int i = tid; i < 16*392; i += 512) hlds[i] = 0;

  // wave w owns j in [w*48, w*48+48): 3 j-groups (q) x 3 gates (g); ntile = g*24 + w*3 + q
  int jq[3]; float bh[3][3]; int colb[3][3];
  #pragma unroll
  for (int q=0;q<3;++q) {
    jq[q] = w*48 + q*16 + jl;
    #pragma unroll
    for (int g=0;g<3;++g) {
      bh[q][g]   = bhh[g*384 + jq[q]];
      colb[q][g] = d*1152 + g*384 + jq[q];
    }
  }

  // per-row scan geometry (row r = kq*4+i)
  int cs_[4], ce_[4], tb_[4], br_[4];
  #pragma unroll
  for (int i=0;i<4;++i) {
    int r = kq*4 + i;
    int b = r & (Bp-1);
    int sub = r >> lbp;
    int scid = uk*(16>>lbp) + sub;
    int cs = scid*CHL;
    int ce = min(LSEQ, cs + CHL);
    cs_[i]=cs; ce_[i]=ce; br_[i]=b;
    tb_[i] = fw ? (cs - WARM) : (ce - 1 + WARM);
  }
  const int nsteps = WARM + CHL;

  float hp[4][3];
  #pragma unroll
  for (int i=0;i<4;++i)
    #pragma unroll
    for (int q=0;q<3;++q) hp[i][q] = 0.f;

  const u16* wbase = wpack + (size_t)d*72*12*512;

  __syncthreads();

  for (int s=0; s<nsteps; ++s) {
    // gx loads for this step (nontemporal: keep L2 for weights)
    u16 gxu[4][3][3];
    #pragma unroll
    for (int i=0;i<4;++i) {
      const int t = fw ? (tb_[i] + s) : (tb_[i] - s);
      const int tl = min(LSEQ-1, max(0, t));
      const size_t ro = ((size_t)br_[i]*LSEQ + tl)*NCOL;
      #pragma unroll
      for (int q=0;q<3;++q)
        #pragma unroll
        for (int g=0;g<3;++g)
          gxu[i][q][g] = __builtin_nontemporal_load(gxz + ro + colb[q][g]);
    }
    // gh = h @ whh^T + bhh : 9 accs per wave (3 j-groups x 3 gates), K=384 in 12 frags
    f32x4 acc[3][3];
    #pragma unroll
    for (int q=0;q<3;++q)
      #pragma unroll
      for (int g=0;g<3;++g) { f32x4 a; a[0]=a[1]=a[2]=a[3]=bh[q][g]; acc[q][g]=a; }
    #pragma unroll
    for (int kt=0; kt<12; ++kt) {
      short8 av = *(const short8*)(hlds + jl*392 + kt*32 + kq*8);
      #pragma unroll
      for (int g=0;g<3;++g)
        #pragma unroll
        for (int q=0;q<3;++q) {
          short8 bv = *(const short8*)(wbase + ((size_t)(g*24 + w*3 + q)*12 + kt)*512 + l*8);
          acc[q][g] = __builtin_amdgcn_mfma_f32_16x16x32_bf16(av, bv, acc[q][g], 0,0,0);
        }
    }
    // gates + h update: lane owns (row kq*4+i, j = jq[q])
    u16 hb[4][3];
    #pragma unroll
    for (int i=0;i<4;++i) {
      const int t = fw ? (tb_[i] + s) : (tb_[i] - s);
      const bool invalid = fw ? (t < 0) : (t > LSEQ-1);
      const bool emit = (t >= cs_[i]) & (t < ce_[i]);
      #pragma unroll
      for (int q=0;q<3;++q) {
        float rr = sigmoid_(bf2f(gxu[i][q][0]) + acc[q][0][i]);
        float zz = sigmoid_(bf2f(gxu[i][q][1]) + acc[q][1][i]);
        float nn = tanh_(bf2f(gxu[i][q][2]) + rr*acc[q][2][i]);
        float hv = nn + zz*(hp[i][q]-nn);
        hv = invalid ? 0.f : hv;
        hp[i][q] = hv;
        hb[i][q] = f2bf(hv);
        if (emit)
          __builtin_nontemporal_store(hb[i][q],
            hbuf + (((size_t)d*Bp + br_[i])*LSEQ + t)*384 + jq[q]);
      }
    }
    if (s+1 < nsteps) {
      __syncthreads();                                     // all reads of h_{s-1} done
      #pragma unroll
      for (int i=0;i<4;++i)
        #pragma unroll
        for (int q=0;q<3;++q)
          hlds[(kq*4+i)*392 + jq[q]] = hb[i][q];
      __syncthreads();                                     // h_s complete in LDS
    }
  }
}

// ---------------- combine: y = silu(h_a + h_b) * silu(z) ----------------
__global__ __launch_bounds__(256)
void k_combine(const u16* __restrict__ hbuf, const u16* __restrict__ gxz, u16* __restrict__ y, int Bp)
{
  const int e = blockIdx.x*256 + threadIdx.x;              // 0 .. Bp*2304*96-1 exact
  const int rowi = e / 96;
  const int c8 = e - rowi*96;
  const int jp0 = c8*8;
  const int bb = rowi / LSEQ, ll = rowi - bb*LSEQ;
  const int da = jp0 < 384 ? 0 : 1;
  const int j0 = jp0 < 384 ? jp0 : jp0 - 384;
  const short8 va = *(const short8*)(hbuf + (((size_t)da*Bp + bb)*LSEQ + ll)*384 + j0);
  const short8 vb = *(const short8*)(hbuf + (((size_t)(da+2)*Bp + bb)*LSEQ + ll)*384 + j0);
  const short8 vz = *(const short8*)(gxz + (size_t)rowi*NCOL + 4608 + jp0);
  short8 vo;
  #pragma unroll
  for (int k=0;k<8;++k) {
    float a = bf2f((u16)va[k]) + bf2f((u16)vb[k]);
    vo[k] = (short)f2bf(silu_(a) * silu_(bf2f((u16)vz[k])));
  }
  *(short8*)(y + (size_t)rowi*768 + jp0) = vo;
}

// ---------------- launch ----------------
extern "C" void kernel_launch(void* const* d_in, const int* in_sizes, int n_in,
                              void* d_out, int out_size, void* d_ws, size_t ws_size,
                              hipStream_t stream)
{
  const float* x     = (const float*)d_in[0];
  const float* ln_g  = (const float*)d_in[1];
  const float* ln_b  = (const float*)d_in[2];
  const float* w_in  = (const float*)d_in[3];
  const float* w_out = (const float*)d_in[4];
  const float* wih[4] = {(const float*)d_in[5], (const float*)d_in[9],  (const float*)d_in[13], (const float*)d_in[17]};
  const float* whh[4] = {(const float*)d_in[6], (const float*)d_in[10], (const float*)d_in[14], (const float*)d_in[18]};
  const float* bih[4] = {(const float*)d_in[7], (const float*)d_in[11], (const float*)d_in[15], (const float*)d_in[19]};
  const float* bhh[4] = {(const float*)d_in[8], (const float*)d_in[12], (const float*)d_in[16], (const float*)d_in[20]};

  auto al = [](size_t v)->size_t { return (v + 255) & ~(size_t)255; };
  const size_t PACKB = (size_t)4*72*12*512*2;           // 3.54 MB packed whh frags
  const size_t fixed = al(7077888) + al(589824) + al(589824) + al(4128768) + al(21504)
                     + al(PACKB);
  auto req = [&](int bp)->size_t {
    return fixed + al((size_t)bp*LSEQ*NCOL*2)           // gxz
                 + al((size_t)bp*4*LSEQ*384*2)          // hbuf
                 + al((size_t)bp*LSEQ*768*2);           // y (xn aliases y)
  };
  int Bp = 1;
  for (int bp = 16; bp >= 1; bp >>= 1) { if (req(bp) <= ws_size) { Bp = bp; break; } }
  if (req(1) > ws_size) return;                         // cannot run at all (diagnostic)
  int lbp = 0; while ((1<<lbp) < Bp) ++lbp;
  const int SC  = NCHUNK*(16/Bp);                       // sub-chunks per (dir,batch)
  const int CHL = (LSEQ + SC - 1)/SC;

  char* ws = (char*)d_ws;
  size_t o = 0;
  auto take = [&](size_t bytes)->char* { char* r = ws + o; o += al(bytes); return r; };
  u16*  wihcat = (u16*)take(7077888);
  u16*  winxT  = (u16*)take(589824);
  u16*  woutB  = (u16*)take(589824);
  u16*  Wcat   = (u16*)take(4128768);
  float* biasf = (float*)take(21504);
  u16*  wpackp = (u16*)take(PACKB);
  u16*  gxzp   = (u16*)take((size_t)Bp*LSEQ*NCOL*2);
  u16*  hbufp  = (u16*)take((size_t)Bp*4*LSEQ*384*2);
  u16*  yp     = (u16*)take((size_t)Bp*LSEQ*768*2);
  u16*  xnp    = yp;                                    // xn dead before y is written

  // one-time weight prep
  k_cvt_wih <<<4096, 256, 0, stream>>>(wih[0],wih[1],wih[2],wih[3], wihcat);
  k_tr_winx <<<1152, 256, 0, stream>>>(w_in, winxT);
  k_cvt_winz<<<1152, 256, 0, stream>>>(w_in, Wcat + (size_t)4608*384);
  k_cvt_wout<<<1152, 256, 0, stream>>>(w_out, woutB);
  k_bias    <<<21,   256, 0, stream>>>(bih[0],bih[1],bih[2],bih[3], biasf);
  k_pack    <<<864,  256, 0, stream>>>(whh[0],whh[1],whh[2],whh[3], wpackp);
  // W_comb = wih_all @ w_in_x : [4608,384]
  k_gemm<0><<<dim3(36,3), 512, 0, stream>>>(wihcat, winxT, Wcat, nullptr, nullptr, nullptr, 768);

  const int npass = 16 / Bp;
  for (int pass = 0; pass < npass; ++pass) {
    const size_t b0row = (size_t)pass * Bp * LSEQ;      // global row offset
    k_ln <<<Bp*576, 256, 0, stream>>>(x + b0row*384, ln_g, ln_b, xnp);
    // gx||z = xn @ Wcat^T + bias : [Bp*2304, 5376]
    k_gemm<1><<<dim3(Bp*18,42), 512, 0, stream>>>(xnp, Wcat, gxzp, nullptr, biasf, nullptr, 384);
    // 4-direction chunked GRU scans, single-WG units
    k_scan2 <<<240, 512, 0, stream>>>(wpackp, bhh[0],bhh[1],bhh[2],bhh[3],
                                      gxzp, hbufp, Bp, lbp, CHL);
    k_combine <<<Bp*864, 256, 0, stream>>>(hbufp, gxzp, yp, Bp);
    // out = x + y @ w_out^T  (FP32 store to d_out)
    k_gemm<2><<<dim3(Bp*18,3), 512, 0, stream>>>(yp, woutB, nullptr, (float*)d_out + b0row*384,
                                                 nullptr, x + b0row*384, 768);
  }
}

// Round 5
// 6592.695 us; speedup vs baseline: 2.0050x; 1.0363x over previous
//
#include <hip/hip_runtime.h>
#include <hip/hip_bf16.h>
#include <stdint.h>

typedef __attribute__((ext_vector_type(8))) short short8;
typedef __attribute__((ext_vector_type(4))) float f32x4;
typedef unsigned short u16;
typedef unsigned int   u32;
typedef unsigned long long u64;

#define DEV static __device__ __forceinline__

DEV float bf2f(u16 u){ return __uint_as_float((u32)u << 16); }
DEV u16 f2bf(float f){ u32 i = __float_as_uint(f); return (u16)((i + 0x7FFFu + ((i>>16)&1u)) >> 16); }
DEV float sigmoid_(float x){ return 1.f/(1.f + __expf(-x)); }
DEV float tanh_(float x){ float a=fabsf(x); float e=__expf(-2.f*a); float r=(1.f-e)/(1.f+e); return x<0.f? -r:r; }
DEV float silu_(float x){ return x/(1.f + __expf(-x)); }

DEV void gload_lds16(const u16* g, u16* l){
  __builtin_amdgcn_global_load_lds((const __attribute__((address_space(1))) void*)g,
                                   (__attribute__((address_space(3))) void*)l, 16, 0, 0);
}

// ---------------- problem constants ----------------
// B=16 H=48 W=48 C=384, L=2304, d_inner=768, hid=384, 3h=1152
#define LSEQ 2304
#define NCOL 5376
#define NCHUNK 60          // units per direction (single-WG units)
#define WARM 32

// ---------------- GEMM: C[m][n] = sum_k A[m][k]*B[n][k]  (A,B bf16 [*,K] k-contig) ----------------
// EPI: 0 = plain bf16 store, 1 = +bias[n] bf16 store, 2 = +resid[m*N+n] fp32 -> FP32 store
template<int EPI>
__global__ __launch_bounds__(512, 2)
void k_gemm(const u16* __restrict__ A, const u16* __restrict__ Bm, u16* __restrict__ Cout,
            float* __restrict__ Fout,
            const float* __restrict__ bias, const float* __restrict__ resid, int K_)
{
  __shared__ u16 ldsA[128*64];
  __shared__ u16 ldsB[128*64];
  const int N   = gridDim.y * 128;
  const int tid = threadIdx.x, l = tid & 63, wid = tid >> 6;
  const int wm = wid >> 2, wn = wid & 3;          // 2 x 4 wave grid, wave tile 64x32
  const int bm = blockIdx.x, bn = blockIdx.y;
  const int jl = l & 15, kq = l >> 4;

  f32x4 acc[4][2];
  #pragma unroll
  for (int a=0;a<4;++a)
    #pragma unroll
    for (int b=0;b<2;++b) acc[a][b] = (f32x4){0.f,0.f,0.f,0.f};

  const u16* Abase = A  + (size_t)bm*128*K_;
  const u16* Bbase = Bm + (size_t)bn*128*K_;
  const int nK = K_ >> 6;
  for (int ks=0; ks<nK; ++ks) {
    __syncthreads();
    #pragma unroll
    for (int p=0;p<2;++p) {
      int row = p*64 + wid*8 + (l>>3);
      int ch  = l & 7;
      gload_lds16(Abase + (size_t)row*K_ + ks*64 + ((ch ^ (row&7))<<3), ldsA + p*4096 + wid*512);
      gload_lds16(Bbase + (size_t)row*K_ + ks*64 + ((ch ^ (row&7))<<3), ldsB + p*4096 + wid*512);
    }
    __syncthreads();
    #pragma unroll
    for (int kt=0; kt<2; ++kt) {
      short8 av[4], bv[2];
      #pragma unroll
      for (int mt=0; mt<4; ++mt) {
        int r = wm*64 + mt*16 + jl;
        int c = kt*4 + kq;
        av[mt] = *(const short8*)(ldsA + r*64 + ((c ^ (r&7))<<3));
      }
      #pragma unroll
      for (int nt=0; nt<2; ++nt) {
        int r = wn*32 + nt*16 + jl;
        int c = kt*4 + kq;
        bv[nt] = *(const short8*)(ldsB + r*64 + ((c ^ (r&7))<<3));
      }
      #pragma unroll
      for (int mt=0; mt<4; ++mt)
        #pragma unroll
        for (int nt=0; nt<2; ++nt)
          acc[mt][nt] = __builtin_amdgcn_mfma_f32_16x16x32_bf16(av[mt], bv[nt], acc[mt][nt], 0,0,0);
    }
  }
  #pragma unroll
  for (int mt=0; mt<4; ++mt)
    #pragma unroll
    for (int nt=0; nt<2; ++nt)
      #pragma unroll
      for (int i=0;i<4;++i) {
        int m = bm*128 + wm*64 + mt*16 + kq*4 + i;   // D row = (lane>>4)*4+reg
        int n = bn*128 + wn*32 + nt*16 + jl;         // D col = lane&15
        float v = acc[mt][nt][i];
        if (EPI==1) v += bias[n];
        if (EPI==2) {
          v += resid[(size_t)m*N + n];
          Fout[(size_t)m*N + n] = v;                 // fp32 output
        } else {
          Cout[(size_t)m*N + n] = f2bf(v);
        }
      }
}

// ---------------- LayerNorm: one wave per row of 384 ----------------
__global__ __launch_bounds__(256)
void k_ln(const float* __restrict__ x, const float* __restrict__ gg, const float* __restrict__ bb,
          u16* __restrict__ xn)
{
  const int row = blockIdx.x*4 + (threadIdx.x>>6);
  const int l = threadIdx.x & 63;
  const float* xr = x + (size_t)row*384;
  float v[6]; float s = 0.f, q = 0.f;
  #pragma unroll
  for (int k=0;k<6;++k){ v[k] = xr[l + 64*k]; s += v[k]; q += v[k]*v[k]; }
  #pragma unroll
  for (int off=32; off; off>>=1){ s += __shfl_xor(s, off); q += __shfl_xor(q, off); }
  const float mean = s * (1.f/384.f);
  const float var  = q * (1.f/384.f) - mean*mean;
  const float rs   = rsqrtf(var + 1e-5f);
  u16* o = xn + (size_t)row*384;
  #pragma unroll
  for (int k=0;k<6;++k){ int c = l + 64*k; o[c] = f2bf((v[k]-mean)*rs*gg[c] + bb[c]); }
}

// ---------------- small converts ----------------
__global__ void k_cvt_wih(const float* a0,const float* a1,const float* a2,const float* a3, u16* out){
  const int per = 1152*768;
  for (int i = blockIdx.x*blockDim.x + threadIdx.x; i < 4*per; i += gridDim.x*blockDim.x) {
    int dd = i / per; int rem = i - dd*per;
    const float* s = dd==0?a0 : dd==1?a1 : dd==2?a2 : a3;
    out[i] = f2bf(s[rem]);
  }
}
__global__ void k_tr_winx(const float* w_in, u16* out){        // out[c*768+k] = w_in[k*384+c], k<768
  for (int i = blockIdx.x*blockDim.x + threadIdx.x; i < 384*768; i += gridDim.x*blockDim.x) {
    int c = i / 768, k = i - c*768;
    out[i] = f2bf(w_in[(size_t)k*384 + c]);
  }
}
__global__ void k_cvt_winz(const float* w_in, u16* dst){
  for (int i = blockIdx.x*blockDim.x + threadIdx.x; i < 768*384; i += gridDim.x*blockDim.x)
    dst[i] = f2bf(w_in[768*384 + i]);
}
__global__ void k_cvt_wout(const float* w_out, u16* dst){
  for (int i = blockIdx.x*blockDim.x + threadIdx.x; i < 384*768; i += gridDim.x*blockDim.x)
    dst[i] = f2bf(w_out[i]);
}
__global__ void k_bias(const float* b0,const float* b1,const float* b2,const float* b3, float* bias){
  for (int i = blockIdx.x*blockDim.x + threadIdx.x; i < NCOL; i += gridDim.x*blockDim.x) {
    float v = 0.f;
    if (i < 4608) { int dd = i/1152, r = i - dd*1152;
      v = (dd==0?b0: dd==1?b1: dd==2?b2: b3)[r]; }
    bias[i] = v;
  }
}

// ---------------- pack whh into MFMA B-fragment order ----------------
// wp[((d*72 + nt)*12 + kt)*512 + l*8 + e] = bf16(whh_d[nt*16 + (l&15)][kt*32 + (l>>4)*8 + e])
// -> a wave's frag load is lanes 0..63 x contiguous 16B = one coalesced 1KB dwordx4 burst.
__global__ void k_pack(const float* w0,const float* w1,const float* w2,const float* w3, u16* wp){
  int idx = blockIdx.x*256 + threadIdx.x;          // 4*72*12*64 = 221184 lane-slots
  if (idx >= 4*72*12*64) return;
  int l = idx & 63; int t = idx >> 6;
  int kt = t % 12; t /= 12;
  int nt = t % 72; int d = t / 72;
  const float* w = d==0?w0 : d==1?w1 : d==2?w2 : w3;
  int row = nt*16 + (l&15);
  int k0  = kt*32 + (l>>4)*8;
  u16* o = wp + (size_t)idx*8;
  #pragma unroll
  for (int e=0;e<8;++e) o[e] = f2bf(w[(size_t)row*384 + k0 + e]);
}

// ---------------- single-WG chunked GRU scan, async LDS weight streaming ----------------
// 240 WGs = 4 dirs x 60 units; one WG owns all 384 hidden dims for 16 rows.
// Weights stream via global_load_lds double-buffer (2 kt-slots x 72KB). Each wave stages
// ONLY the 9 fragments it computes -> no barriers for weights; per-wave vmcnt(9) discipline.
// h handoff uses raw s_barrier + lgkmcnt(0) so the vm staging queue stays in flight.
__global__ __launch_bounds__(512, 1)
void k_scan3(const u16* __restrict__ wpack,
             const float* __restrict__ bhh0, const float* __restrict__ bhh1,
             const float* __restrict__ bhh2, const float* __restrict__ bhh3,
             const u16* __restrict__ gxz, u16* __restrict__ hbuf,
             int Bp, int lbp, int CHL)
{
  const int blk = blockIdx.x;
  const int d  = blk & 3;                 // dir; blk%8 XCD heuristic -> dir-per-XCD L2 affinity
  const int uk = blk >> 2;                // unit index within dir, [0,60)
  const bool fw = (d==0) || (d==3);
  const float* bhh = d==0?bhh0 : d==1?bhh1 : d==2?bhh2 : bhh3;

  const int tid = threadIdx.x, l = tid & 63, w = tid >> 6;   // 8 waves
  const int jl = l & 15, kq = l >> 4;

  __shared__ u16 ldsW[2*8*9*512];         // 147456 B: [slot][wave][frag g*3+q][lane*8 u16]
  __shared__ u16 hlds[16*392];            // 12544 B: h bf16 [16 rows][384+pad]
  for (int i = tid; i < 16*392; i += 512) hlds[i] = 0;

  // wave w owns j in [w*48, w*48+48): 3 j-groups (q) x 3 gates (g)
  int jq[3]; float bh[3][3]; int colb[3][3];
  #pragma unroll
  for (int q=0;q<3;++q) {
    jq[q] = w*48 + q*16 + jl;
    #pragma unroll
    for (int g=0;g<3;++g) {
      bh[q][g]   = bhh[g*384 + jq[q]];
      colb[q][g] = d*1152 + g*384 + jq[q];
    }
  }

  // per-row scan geometry (row r = kq*4+i)
  int cs_[4], ce_[4], tb_[4], br_[4];
  #pragma unroll
  for (int i=0;i<4;++i) {
    int r = kq*4 + i;
    int b = r & (Bp-1);
    int sub = r >> lbp;
    int scid = uk*(16>>lbp) + sub;
    int cs = scid*CHL;
    int ce = min(LSEQ, cs + CHL);
    cs_[i]=cs; ce_[i]=ce; br_[i]=b;
    tb_[i] = fw ? (cs - WARM) : (ce - 1 + WARM);
  }
  const int nsteps = WARM + CHL;

  float hp[4][3];
  #pragma unroll
  for (int i=0;i<4;++i)
    #pragma unroll
    for (int q=0;q<3;++q) hp[i][q] = 0.f;

  // fragment addressing: frag f = g*3+q; global u16-offset = (ntile*12 + kt)*512
  const u16* wdir = wpack + (size_t)d*72*12*512;
  u32 goff[9];
  #pragma unroll
  for (int g=0;g<3;++g)
    #pragma unroll
    for (int q=0;q<3;++q)
      goff[g*3+q] = (u32)((g*24 + w*3 + q)*12)*512;

  // prologue: stage kt=0 -> slot0, kt=1 -> slot1 (9 x 1KB per wave per slot)
  #pragma unroll
  for (int kt0=0; kt0<2; ++kt0)
    #pragma unroll
    for (int f=0; f<9; ++f)
      gload_lds16(wdir + goff[f] + kt0*512 + l*8, ldsW + ((kt0*8 + w)*9 + f)*512);

  __syncthreads();                        // h zero-init visible (one-time vmcnt drain, ok)

  for (int s=0; s<nsteps; ++s) {
    // gx loads for this step (nontemporal; ~12 phases of latency cover before gates)
    u16 gxu[4][3][3];
    #pragma unroll
    for (int i=0;i<4;++i) {
      const int t = fw ? (tb_[i] + s) : (tb_[i] - s);
      const int tl = min(LSEQ-1, max(0, t));
      const size_t ro = ((size_t)br_[i]*LSEQ + tl)*NCOL;
      #pragma unroll
      for (int q=0;q<3;++q)
        #pragma unroll
        for (int g=0;g<3;++g)
          gxu[i][q][g] = __builtin_nontemporal_load(gxz + ro + colb[q][g]);
    }

    f32x4 acc[3][3];
    #pragma unroll
    for (int q=0;q<3;++q)
      #pragma unroll
      for (int g=0;g<3;++g) { f32x4 a; a[0]=a[1]=a[2]=a[3]=bh[q][g]; acc[q][g]=a; }

    #pragma unroll
    for (int kt=0; kt<12; ++kt) {
      // wave-local: wait until my stage(kt) landed (keep newest 9 = stage(kt+1) in flight)
      asm volatile("s_waitcnt vmcnt(9)" ::: "memory");
      __builtin_amdgcn_sched_barrier(0);
      const int slot = kt & 1;
      short8 av = *(const short8*)(hlds + jl*392 + kt*32 + kq*8);
      short8 bv[9];
      #pragma unroll
      for (int f=0; f<9; ++f)
        bv[f] = *(const short8*)(ldsW + ((slot*8 + w)*9 + f)*512 + l*8);
      #pragma unroll
      for (int g=0;g<3;++g)
        #pragma unroll
        for (int q=0;q<3;++q)
          acc[q][g] = __builtin_amdgcn_mfma_f32_16x16x32_bf16(av, bv[g*3+q], acc[q][g], 0,0,0);
      // my ds_reads of this slot retired -> safe to overwrite slot with stage(kt+2)
      asm volatile("s_waitcnt lgkmcnt(0)" ::: "memory");
      __builtin_amdgcn_sched_barrier(0);
      const int kt2 = (kt+2 < 12) ? (kt+2) : (kt+2-12);   // same weights every step
      #pragma unroll
      for (int f=0; f<9; ++f)
        gload_lds16(wdir + goff[f] + kt2*512 + l*8, ldsW + ((slot*8 + w)*9 + f)*512);
    }

    // gates + h update: lane owns (row kq*4+i, j = jq[q])
    u16 hb[4][3];
    #pragma unroll
    for (int i=0;i<4;++i) {
      const int t = fw ? (tb_[i] + s) : (tb_[i] - s);
      const bool invalid = fw ? (t < 0) : (t > LSEQ-1);
      const bool emit = (t >= cs_[i]) & (t < ce_[i]);
      #pragma unroll
      for (int q=0;q<3;++q) {
        float rr = sigmoid_(bf2f(gxu[i][q][0]) + acc[q][0][i]);
        float zz = sigmoid_(bf2f(gxu[i][q][1]) + acc[q][1][i]);
        float nn = tanh_(bf2f(gxu[i][q][2]) + rr*acc[q][2][i]);
        float hv = nn + zz*(hp[i][q]-nn);
        hv = invalid ? 0.f : hv;
        hp[i][q] = hv;
        hb[i][q] = f2bf(hv);
        if (emit)
          __builtin_nontemporal_store(hb[i][q],
            hbuf + (((size_t)d*Bp + br_[i])*LSEQ + t)*384 + jq[q]);
      }
    }

    if (s+1 < nsteps) {
      // raw barriers: no vmcnt drain -> weight staging pipeline survives the step boundary
      asm volatile("s_waitcnt lgkmcnt(0)" ::: "memory");
      __builtin_amdgcn_sched_barrier(0);
      __builtin_amdgcn_s_barrier();                      // all reads of h_{s-1} done
      #pragma unroll
      for (int i=0;i<4;++i)
        #pragma unroll
        for (int q=0;q<3;++q)
          hlds[(kq*4+i)*392 + jq[q]] = hb[i][q];
      asm volatile("s_waitcnt lgkmcnt(0)" ::: "memory");
      __builtin_amdgcn_sched_barrier(0);
      __builtin_amdgcn_s_barrier();                      // h_s visible to all waves
    }
  }
}

// ---------------- combine: y = silu(h_a + h_b) * silu(z) ----------------
__global__ __launch_bounds__(256)
void k_combine(const u16* __restrict__ hbuf, const u16* __restrict__ gxz, u16* __restrict__ y, int Bp)
{
  const int e = blockIdx.x*256 + threadIdx.x;              // 0 .. Bp*2304*96-1 exact
  const int rowi = e / 96;
  const int c8 = e - rowi*96;
  const int jp0 = c8*8;
  const int bb = rowi / LSEQ, ll = rowi - bb*LSEQ;
  const int da = jp0 < 384 ? 0 : 1;
  const int j0 = jp0 < 384 ? jp0 : jp0 - 384;
  const short8 va = *(const short8*)(hbuf + (((size_t)da*Bp + bb)*LSEQ + ll)*384 + j0);
  const short8 vb = *(const short8*)(hbuf + (((size_t)(da+2)*Bp + bb)*LSEQ + ll)*384 + j0);
  const short8 vz = *(const short8*)(gxz + (size_t)rowi*NCOL + 4608 + jp0);
  short8 vo;
  #pragma unroll
  for (int k=0;k<8;++k) {
    float a = bf2f((u16)va[k]) + bf2f((u16)vb[k]);
    vo[k] = (short)f2bf(silu_(a) * silu_(bf2f((u16)vz[k])));
  }
  *(short8*)(y + (size_t)rowi*768 + jp0) = vo;
}

// ---------------- launch ----------------
extern "C" void kernel_launch(void* const* d_in, const int* in_sizes, int n_in,
                              void* d_out, int out_size, void* d_ws, size_t ws_size,
                              hipStream_t stream)
{
  const float* x     = (const float*)d_in[0];
  const float* ln_g  = (const float*)d_in[1];
  const float* ln_b  = (const float*)d_in[2];
  const float* w_in  = (const float*)d_in[3];
  const float* w_out = (const float*)d_in[4];
  const float* wih[4] = {(const float*)d_in[5], (const float*)d_in[9],  (const float*)d_in[13], (const float*)d_in[17]};
  const float* whh[4] = {(const float*)d_in[6], (const float*)d_in[10], (const float*)d_in[14], (const float*)d_in[18]};
  const float* bih[4] = {(const float*)d_in[7], (const float*)d_in[11], (const float*)d_in[15], (const float*)d_in[19]};
  const float* bhh[4] = {(const float*)d_in[8], (const float*)d_in[12], (const float*)d_in[16], (const float*)d_in[20]};

  auto al = [](size_t v)->size_t { return (v + 255) & ~(size_t)255; };
  const size_t PACKB = (size_t)4*72*12*512*2;           // 3.54 MB packed whh frags
  const size_t fixed = al(7077888) + al(589824) + al(589824) + al(4128768) + al(21504)
                     + al(PACKB);
  auto req = [&](int bp)->size_t {
    return fixed + al((size_t)bp*LSEQ*NCOL*2)           // gxz
                 + al((size_t)bp*4*LSEQ*384*2)          // hbuf
                 + al((size_t)bp*LSEQ*768*2);           // y (xn aliases y)
  };
  int Bp = 1;
  for (int bp = 16; bp >= 1; bp >>= 1) { if (req(bp) <= ws_size) { Bp = bp; break; } }
  if (req(1) > ws_size) return;                         // cannot run at all (diagnostic)
  int lbp = 0; while ((1<<lbp) < Bp) ++lbp;
  const int SC  = NCHUNK*(16/Bp);                       // sub-chunks per (dir,batch)
  const int CHL = (LSEQ + SC - 1)/SC;

  char* ws = (char*)d_ws;
  size_t o = 0;
  auto take = [&](size_t bytes)->char* { char* r = ws + o; o += al(bytes); return r; };
  u16*  wihcat = (u16*)take(7077888);
  u16*  winxT  = (u16*)take(589824);
  u16*  woutB  = (u16*)take(589824);
  u16*  Wcat   = (u16*)take(4128768);
  float* biasf = (float*)take(21504);
  u16*  wpackp = (u16*)take(PACKB);
  u16*  gxzp   = (u16*)take((size_t)Bp*LSEQ*NCOL*2);
  u16*  hbufp  = (u16*)take((size_t)Bp*4*LSEQ*384*2);
  u16*  yp     = (u16*)take((size_t)Bp*LSEQ*768*2);
  u16*  xnp    = yp;                                    // xn dead before y is written

  // one-time weight prep
  k_cvt_wih <<<4096, 256, 0, stream>>>(wih[0],wih[1],wih[2],wih[3], wihcat);
  k_tr_winx <<<1152, 256, 0, stream>>>(w_in, winxT);
  k_cvt_winz<<<1152, 256, 0, stream>>>(w_in, Wcat + (size_t)4608*384);
  k_cvt_wout<<<1152, 256, 0, stream>>>(w_out, woutB);
  k_bias    <<<21,   256, 0, stream>>>(bih[0],bih[1],bih[2],bih[3], biasf);
  k_pack    <<<864,  256, 0, stream>>>(whh[0],whh[1],whh[2],whh[3], wpackp);
  // W_comb = wih_all @ w_in_x : [4608,384]
  k_gemm<0><<<dim3(36,3), 512, 0, stream>>>(wihcat, winxT, Wcat, nullptr, nullptr, nullptr, 768);

  const int npass = 16 / Bp;
  for (int pass = 0; pass < npass; ++pass) {
    const size_t b0row = (size_t)pass * Bp * LSEQ;      // global row offset
    k_ln <<<Bp*576, 256, 0, stream>>>(x + b0row*384, ln_g, ln_b, xnp);
    // gx||z = xn @ Wcat^T + bias : [Bp*2304, 5376]
    k_gemm<1><<<dim3(Bp*18,42), 512, 0, stream>>>(xnp, Wcat, gxzp, nullptr, biasf, nullptr, 384);
    // 4-direction chunked GRU scans, single-WG units, async weight streaming
    k_scan3 <<<240, 512, 0, stream>>>(wpackp, bhh[0],bhh[1],bhh[2],bhh[3],
                                      gxzp, hbufp, Bp, lbp, CHL);
    k_combine <<<Bp*864, 256, 0, stream>>>(hbufp, gxzp, yp, Bp);
    // out = x + y @ w_out^T  (FP32 store to d_out)
    k_gemm<2><<<dim3(Bp*18,3), 512, 0, stream>>>(yp, woutB, nullptr, (float*)d_out + b0row*384,
                                                 nullptr, x + b0row*384, 768);
  }
}